// Round 3
// baseline (412.842 us; speedup 1.0000x reference)
//
#include <hip/hip_runtime.h>
#include <math.h>

#define DEVFN __global__ __launch_bounds__(256)

namespace {
constexpr int LL  = 128;   // L
constexpr int MM2 = 255;   // 2L-1
constexpr int NT  = 256;   // ntheta
constexpr int NP  = 512;   // nphi
constexpr int NC  = 32;    // C_IN
constexpr int NO  = 32;    // C_OUT
constexpr float TWO_PI = 6.283185307179586476925286766559f;
}

typedef short v8s __attribute__((ext_vector_type(8)));   // 8 bf16 (4 VGPRs)
typedef float v4f __attribute__((ext_vector_type(4)));   // 4 fp32 acc

__device__ inline unsigned short f2bf(float f) {
  unsigned int u = __float_as_uint(f);
  return (unsigned short)((u + 0x7FFFu + ((u >> 16) & 1u)) >> 16);  // RNE
}

// ---------------------------------------------------------------- KP: prep (twiddles + x transpose)
// blocks [0,512):   tw1t[n][p] (256x512): n=2m -> cos(2pi m p/512)*(2pi/512), n=2m+1 -> -sin*(2pi/512)
//                   vt[p][k]   (512x256): k=2m -> cos(2pi m p/512),           k=2m+1 -> sin
// blocks [512,2560): xb[r=(t*32+c)][p] bf16 from x[t][p][c]
DEVFN void kp_prep(const float* __restrict__ x, unsigned short* __restrict__ tw1t,
                   unsigned short* __restrict__ vt, unsigned short* __restrict__ xb) {
  __shared__ float sm[32][65];
  const int bid = blockIdx.x;
  const int tid = threadIdx.x;
  const float phi = TWO_PI / (float)NP;
  if (bid < 512) {
    const int idx = bid * 256 + tid;  // 0..131071
    const float fs = TWO_PI / (float)NP;
    {
      const int n = idx >> 9, p = idx & 511;
      const int m = n >> 1;
      const int k = (m * p) & (NP - 1);
      float s, c;
      sincosf(phi * (float)k, &s, &c);
      tw1t[idx] = f2bf((n & 1) ? (-s * fs) : (c * fs));
    }
    {
      const int p = idx >> 8, k = idx & 255;
      const int m = k >> 1;
      const int kk = (m * p) & (NP - 1);
      float s, c;
      sincosf(phi * (float)kk, &s, &c);
      vt[idx] = f2bf((k & 1) ? s : c);
    }
  } else {
    const int q = bid - 512;           // 0..2047
    const int t = q >> 3;
    const int p0 = (q & 7) * 64;
#pragma unroll
    for (int i = 0; i < 8; ++i) {
      const int idx = tid + i * 256;
      const int p = idx >> 5, c = idx & 31;
      sm[c][p] = x[((size_t)t * NP + p0 + p) * NC + c];
    }
    __syncthreads();
    const int c = tid >> 3, pg = tid & 7;
    unsigned short pk[8];
#pragma unroll
    for (int u = 0; u < 8; ++u) pk[u] = f2bf(sm[c][pg * 8 + u]);
    *(uint4*)(xb + ((size_t)(t * 32 + c)) * NP + p0 + pg * 8) = *(const uint4*)pk;
  }
}

// ---------------------------------------------------------------- K1: forward DFT via MFMA
// C[r][n] = sum_p Xb[r][p] * tw1t[n][p];  fw{r,i}[m][t][c] = C * wg[t]   (M=8192,N=256,K=512)
DEVFN void k1_mfma(const unsigned short* __restrict__ xb,
                   const unsigned short* __restrict__ tw1t,
                   const float* __restrict__ wg,
                   float* __restrict__ fwr, float* __restrict__ fwi) {
  __shared__ unsigned short As[128 * 32];
  __shared__ unsigned short Bs[128 * 32];
  const int tid = threadIdx.x;
  const int r0 = blockIdx.x * 128;
  const int n0 = blockIdx.y * 128;
  const int wid = tid >> 6, lane = tid & 63;
  const int wm = wid & 1, wn = wid >> 1;
  v4f acc[4][4];
#pragma unroll
  for (int i = 0; i < 4; ++i)
#pragma unroll
    for (int j = 0; j < 4; ++j) {
      acc[i][j][0] = 0.f; acc[i][j][1] = 0.f; acc[i][j][2] = 0.f; acc[i][j][3] = 0.f;
    }
  const int lr = lane & 15, lk = (lane >> 4) * 8;
  for (int k0 = 0; k0 < 512; k0 += 32) {
#pragma unroll
    for (int s = 0; s < 2; ++s) {
      const int chunk = tid + s * 256;      // 512 chunks x 16B
      const int row = chunk >> 2, c16 = chunk & 3;
      *(uint4*)&As[row * 32 + c16 * 8] =
          *(const uint4*)&xb[(size_t)(r0 + row) * 512 + k0 + c16 * 8];
      *(uint4*)&Bs[row * 32 + c16 * 8] =
          *(const uint4*)&tw1t[(size_t)(n0 + row) * 512 + k0 + c16 * 8];
    }
    __syncthreads();
    v8s af[4], bf[4];
#pragma unroll
    for (int i = 0; i < 4; ++i) af[i] = *(const v8s*)&As[(wm * 64 + i * 16 + lr) * 32 + lk];
#pragma unroll
    for (int j = 0; j < 4; ++j) bf[j] = *(const v8s*)&Bs[(wn * 64 + j * 16 + lr) * 32 + lk];
#pragma unroll
    for (int i = 0; i < 4; ++i)
#pragma unroll
      for (int j = 0; j < 4; ++j)
        acc[i][j] = __builtin_amdgcn_mfma_f32_16x16x32_bf16(af[i], bf[j], acc[i][j], 0, 0, 0);
    __syncthreads();
  }
  // Epilogue: the 4 acc regs walk r (= 4 consecutive c at fixed t) -> one float4 store.
  const int lrow = (lane >> 4) * 4;
#pragma unroll
  for (int i = 0; i < 4; ++i) {
    const int rbase = r0 + wm * 64 + i * 16 + lrow;
    const int t = rbase >> 5, c0 = rbase & 31;   // c0 % 4 == 0, c0+3 <= 31
    const float w = wg[t];
#pragma unroll
    for (int j = 0; j < 4; ++j) {
      const int n = n0 + wn * 64 + j * 16 + lr;
      const int mI = n >> 1;
      float* dst = (n & 1) ? fwi : fwr;
      float4 v = {acc[i][j][0] * w, acc[i][j][1] * w, acc[i][j][2] * w, acc[i][j][3] * w};
      *(float4*)&dst[((size_t)mI * NT + t) * NC + c0] = v;
    }
  }
}

// ---------------------------------------------------------------- K2: flm (l >= m only), fp32
DEVFN void k2_flm(const float* __restrict__ leg, const float* __restrict__ fwr,
                  const float* __restrict__ fwi, float* __restrict__ flr,
                  float* __restrict__ fli) {
  const int m = blockIdx.x;
  const int l = m + blockIdx.y * 8 + (threadIdx.x >> 5);
  const int c = threadIdx.x & 31;
  if (l >= LL) return;
  const float* lg = leg + ((size_t)(l * MM2 + 127 + m)) * NT;
  const float* fr = fwr + (size_t)m * NT * NC + c;
  const float* fi = fwi + (size_t)m * NT * NC + c;
  float ar = 0.f, ai = 0.f;
  for (int t = 0; t < NT; t += 4) {
#pragma unroll
    for (int u = 0; u < 4; ++u) {
      const float b = lg[t + u];
      ar = fmaf(b, fr[(t + u) * NC], ar);
      ai = fmaf(b, fi[(t + u) * NC], ai);
    }
  }
  flr[(m * LL + l) * NC + c] = ar;
  fli[(m * LL + l) * NC + c] = ai;
}

// ---------------------------------------------------------------- K3: channel mix (HBM-bound)
DEVFN void k3_y(const float* __restrict__ wr, const float* __restrict__ wi,
                const float* __restrict__ flr, const float* __restrict__ fli,
                float* __restrict__ ya, float* __restrict__ yb) {
  const int m = blockIdx.x;
  const int lbase = m + (int)blockIdx.y * 32;
  if (lbase >= LL) return;
  __shared__ float sfr[32][33];
  __shared__ float sfi[32][33];
  const int tid = threadIdx.x;
  for (int i = tid; i < 1024; i += 256) {
    const int lr2 = i >> 5, cc = i & 31;
    const int l = lbase + lr2;
    sfr[lr2][cc] = (l < LL) ? flr[(m * LL + l) * NC + cc] : 0.f;
    sfi[lr2][cc] = (l < LL) ? fli[(m * LL + l) * NC + cc] : 0.f;
  }
  __syncthreads();
  const int lo = tid >> 3;
  const int o4 = (tid & 7) << 2;
  const int l = lbase + lo;
  if (l >= LL) return;
  const float s0 = (m > 0) ? 1.0f : 0.0f;
  const size_t base_p = ((size_t)(l * MM2 + 127 + m) * NC) * NO + o4;
  const size_t base_n = ((size_t)(l * MM2 + 127 - m) * NC) * NO + o4;
  float ax = 0, ay = 0, az = 0, aw = 0;
  float bx = 0, by = 0, bz = 0, bw = 0;
#pragma unroll 4
  for (int c = 0; c < NC; ++c) {
    const float fr = sfr[lo][c], fi = sfi[lo][c];
    const float4 pr = *(const float4*)(wr + base_p + c * NO);
    const float4 nr = *(const float4*)(wr + base_n + c * NO);
    const float4 pi = *(const float4*)(wi + base_p + c * NO);
    const float4 ni = *(const float4*)(wi + base_n + c * NO);
    const float wax = pr.x + s0 * nr.x, way = pr.y + s0 * nr.y,
                waz = pr.z + s0 * nr.z, waw = pr.w + s0 * nr.w;
    const float wbx = s0 * ni.x - pi.x, wby = s0 * ni.y - pi.y,
                wbz = s0 * ni.z - pi.z, wbw = s0 * ni.w - pi.w;
    ax = fmaf(fr, wax, fmaf(fi, wbx, ax));
    ay = fmaf(fr, way, fmaf(fi, wby, ay));
    az = fmaf(fr, waz, fmaf(fi, wbz, az));
    aw = fmaf(fr, waw, fmaf(fi, wbw, aw));
    bx = fmaf(fr, wbx, fmaf(-fi, wax, bx));
    by = fmaf(fr, wby, fmaf(-fi, way, by));
    bz = fmaf(fr, wbz, fmaf(-fi, waz, bz));
    bw = fmaf(fr, wbw, fmaf(-fi, waw, bw));
  }
  float4 va = {ax, ay, az, aw}, vb = {bx, by, bz, bw};
  *(float4*)(ya + (size_t)(m * LL + l) * NO + o4) = va;
  *(float4*)(yb + (size_t)(m * LL + l) * NO + o4) = vb;
}

// ---------------------------------------------------------------- K4: inverse Legendre -> Ut bf16
// Ut[r=(t*32+o)][k] : k=2m -> cos coeff, k=2m+1 -> sin coeff
DEVFN void k4_G(const float* __restrict__ leg, const float* __restrict__ ya,
                const float* __restrict__ yb, unsigned short* __restrict__ ut) {
  const int m = blockIdx.x;
  const int o = threadIdx.x & 31;
  const int tq = threadIdx.x >> 5;
  const int t0 = blockIdx.y * 32 + tq * 4;
  float aa[4] = {}, bb[4] = {};
  for (int l = m; l < LL; ++l) {
    const float* lgl = leg + ((size_t)(l * MM2 + 127 + m)) * NT + t0;
    const float yav = ya[(m * LL + l) * NO + o];
    const float ybv = yb[(m * LL + l) * NO + o];
#pragma unroll
    for (int i = 0; i < 4; ++i) {
      const float g = lgl[i];
      aa[i] = fmaf(g, yav, aa[i]);
      bb[i] = fmaf(g, ybv, bb[i]);
    }
  }
#pragma unroll
  for (int i = 0; i < 4; ++i) {
    const unsigned int pk = (unsigned int)f2bf(aa[i]) | ((unsigned int)f2bf(bb[i]) << 16);
    *(unsigned int*)&ut[((size_t)((t0 + i) * 32 + o)) * 256 + 2 * m] = pk;
  }
}

// ---------------------------------------------------------------- K5: inverse DFT via MFMA (A=vt!)
// D[p][r] = sum_k vt[p][k] * ut[r][k];  out[o][t][p] = D,  r=t*32+o   (M=512,N=8192,K=256)
// Operand swap puts the acc reg-dim on p (out's fastest axis) -> float4 stores.
DEVFN void k5_mfma(const unsigned short* __restrict__ ut,
                   const unsigned short* __restrict__ vt,
                   float* __restrict__ out) {
  __shared__ unsigned short As[128 * 32];  // vt tile (p rows)
  __shared__ unsigned short Bs[128 * 32];  // ut tile (r rows)
  const int tid = threadIdx.x;
  const int p0 = blockIdx.x * 128;
  const int r0 = blockIdx.y * 128;
  const int wid = tid >> 6, lane = tid & 63;
  const int wm = wid & 1, wn = wid >> 1;
  v4f acc[4][4];
#pragma unroll
  for (int i = 0; i < 4; ++i)
#pragma unroll
    for (int j = 0; j < 4; ++j) {
      acc[i][j][0] = 0.f; acc[i][j][1] = 0.f; acc[i][j][2] = 0.f; acc[i][j][3] = 0.f;
    }
  const int lr = lane & 15, lk = (lane >> 4) * 8;
  for (int k0 = 0; k0 < 256; k0 += 32) {
#pragma unroll
    for (int s = 0; s < 2; ++s) {
      const int chunk = tid + s * 256;
      const int row = chunk >> 2, c16 = chunk & 3;
      *(uint4*)&As[row * 32 + c16 * 8] =
          *(const uint4*)&vt[(size_t)(p0 + row) * 256 + k0 + c16 * 8];
      *(uint4*)&Bs[row * 32 + c16 * 8] =
          *(const uint4*)&ut[(size_t)(r0 + row) * 256 + k0 + c16 * 8];
    }
    __syncthreads();
    v8s af[4], bf[4];
#pragma unroll
    for (int i = 0; i < 4; ++i) af[i] = *(const v8s*)&As[(wm * 64 + i * 16 + lr) * 32 + lk];
#pragma unroll
    for (int j = 0; j < 4; ++j) bf[j] = *(const v8s*)&Bs[(wn * 64 + j * 16 + lr) * 32 + lk];
#pragma unroll
    for (int i = 0; i < 4; ++i)
#pragma unroll
      for (int j = 0; j < 4; ++j)
        acc[i][j] = __builtin_amdgcn_mfma_f32_16x16x32_bf16(af[i], bf[j], acc[i][j], 0, 0, 0);
    __syncthreads();
  }
  // Epilogue: regs walk p (contiguous in out); quads tile p0..p0+15 -> full 64B lines.
  const int lrow = (lane >> 4) * 4;
#pragma unroll
  for (int i = 0; i < 4; ++i) {
    const int pbase = p0 + wm * 64 + i * 16 + lrow;
#pragma unroll
    for (int j = 0; j < 4; ++j) {
      const int r = r0 + wn * 64 + j * 16 + lr;
      const int t = r >> 5, o = r & 31;
      float4 v = {acc[i][j][0], acc[i][j][1], acc[i][j][2], acc[i][j][3]};
      *(float4*)&out[((size_t)o * NT + t) * NP + pbase] = v;
    }
  }
}

// ---------------------------------------------------------------- launch
extern "C" void kernel_launch(void* const* d_in, const int* in_sizes, int n_in,
                              void* d_out, int out_size, void* d_ws, size_t ws_size,
                              hipStream_t stream) {
  const float* x   = (const float*)d_in[0];
  const float* wr  = (const float*)d_in[1];
  const float* wi  = (const float*)d_in[2];
  const float* leg = (const float*)d_in[3];
  const float* wg  = (const float*)d_in[4];
  float* out = (float*)d_out;

  unsigned short* tw1t = (unsigned short*)d_ws;     // 256*512   = 131072
  unsigned short* vt   = tw1t + 131072;             // 512*256   = 131072
  unsigned short* xb   = vt + 131072;               // 8192*512  = 4194304
  unsigned short* ut   = xb + 4194304;              // 8192*256  = 2097152
  float* fwr = (float*)(ut + 2097152);              // 128*256*32 = 1048576
  float* fwi = fwr + 1048576;
  float* flr = fwi + 1048576;                       // 128*128*32 = 524288
  float* fli = flr + 524288;
  float* ya  = fli + 524288;
  float* yb  = ya + 524288;                         // total ~29.9 MB

  hipLaunchKernelGGL(kp_prep, dim3(2560), dim3(256), 0, stream, x, tw1t, vt, xb);
  hipLaunchKernelGGL(k1_mfma, dim3(64, 2), dim3(256), 0, stream, xb, tw1t, wg, fwr, fwi);
  hipLaunchKernelGGL(k2_flm, dim3(128, 16), dim3(256), 0, stream, leg, fwr, fwi, flr, fli);
  hipLaunchKernelGGL(k3_y, dim3(128, 4), dim3(256), 0, stream, wr, wi, flr, fli, ya, yb);
  hipLaunchKernelGGL(k4_G, dim3(128, 8), dim3(256), 0, stream, leg, ya, yb, ut);
  hipLaunchKernelGGL(k5_mfma, dim3(4, 64), dim3(256), 0, stream, ut, vt, out);
}

// Round 4
// 405.002 us; speedup vs baseline: 1.0194x; 1.0194x over previous
//
#include <hip/hip_runtime.h>
#include <math.h>

#define DEVFN __global__ __launch_bounds__(256)

namespace {
constexpr int LL  = 128;   // L
constexpr int MM2 = 255;   // 2L-1
constexpr int NT  = 256;   // ntheta
constexpr int NP  = 512;   // nphi
constexpr int NC  = 32;    // C_IN
constexpr int NO  = 32;    // C_OUT
constexpr float TWO_PI = 6.283185307179586476925286766559f;
}

typedef short v8s __attribute__((ext_vector_type(8)));   // 8 bf16 (4 VGPRs)
typedef float v4f __attribute__((ext_vector_type(4)));   // 4 fp32 acc

__device__ inline unsigned short f2bf(float f) {
  unsigned int u = __float_as_uint(f);
  return (unsigned short)((u + 0x7FFFu + ((u >> 16) & 1u)) >> 16);  // RNE
}

// ---------------------------------------------------------------- KP: prep (twiddles + x transpose)
DEVFN void kp_prep(const float* __restrict__ x, unsigned short* __restrict__ tw1t,
                   unsigned short* __restrict__ vt, unsigned short* __restrict__ xb) {
  __shared__ float sm[32][65];
  const int bid = blockIdx.x;
  const int tid = threadIdx.x;
  const float phi = TWO_PI / (float)NP;
  if (bid < 512) {
    const int idx = bid * 256 + tid;  // 0..131071
    const float fs = TWO_PI / (float)NP;
    {
      const int n = idx >> 9, p = idx & 511;
      const int m = n >> 1;
      const int k = (m * p) & (NP - 1);
      float s, c;
      sincosf(phi * (float)k, &s, &c);
      tw1t[idx] = f2bf((n & 1) ? (-s * fs) : (c * fs));
    }
    {
      const int p = idx >> 8, k = idx & 255;
      const int m = k >> 1;
      const int kk = (m * p) & (NP - 1);
      float s, c;
      sincosf(phi * (float)kk, &s, &c);
      vt[idx] = f2bf((k & 1) ? s : c);
    }
  } else {
    const int q = bid - 512;           // 0..2047
    const int t = q >> 3;
    const int p0 = (q & 7) * 64;
#pragma unroll
    for (int i = 0; i < 8; ++i) {
      const int idx = tid + i * 256;
      const int p = idx >> 5, c = idx & 31;
      sm[c][p] = x[((size_t)t * NP + p0 + p) * NC + c];
    }
    __syncthreads();
    const int c = tid >> 3, pg = tid & 7;
    unsigned short pk[8];
#pragma unroll
    for (int u = 0; u < 8; ++u) pk[u] = f2bf(sm[c][pg * 8 + u]);
    *(uint4*)(xb + ((size_t)(t * 32 + c)) * NP + p0 + pg * 8) = *(const uint4*)pk;
  }
}

// ---------------------------------------------------------------- K1: forward DFT via MFMA
// C[r][n] = sum_p Xb[r][p] * tw1t[n][p];  fw{r,i}[m][t][c] = C * wg[t]   (M=8192,N=256,K=512)
DEVFN void k1_mfma(const unsigned short* __restrict__ xb,
                   const unsigned short* __restrict__ tw1t,
                   const float* __restrict__ wg,
                   float* __restrict__ fwr, float* __restrict__ fwi) {
  __shared__ unsigned short As[128 * 32];
  __shared__ unsigned short Bs[128 * 32];
  const int tid = threadIdx.x;
  const int r0 = blockIdx.x * 128;
  const int n0 = blockIdx.y * 128;
  const int wid = tid >> 6, lane = tid & 63;
  const int wm = wid & 1, wn = wid >> 1;
  v4f acc[4][4];
#pragma unroll
  for (int i = 0; i < 4; ++i)
#pragma unroll
    for (int j = 0; j < 4; ++j) {
      acc[i][j][0] = 0.f; acc[i][j][1] = 0.f; acc[i][j][2] = 0.f; acc[i][j][3] = 0.f;
    }
  const int lr = lane & 15, lk = (lane >> 4) * 8;
  for (int k0 = 0; k0 < 512; k0 += 32) {
#pragma unroll
    for (int s = 0; s < 2; ++s) {
      const int chunk = tid + s * 256;      // 512 chunks x 16B
      const int row = chunk >> 2, c16 = chunk & 3;
      *(uint4*)&As[row * 32 + c16 * 8] =
          *(const uint4*)&xb[(size_t)(r0 + row) * 512 + k0 + c16 * 8];
      *(uint4*)&Bs[row * 32 + c16 * 8] =
          *(const uint4*)&tw1t[(size_t)(n0 + row) * 512 + k0 + c16 * 8];
    }
    __syncthreads();
    v8s af[4], bf[4];
#pragma unroll
    for (int i = 0; i < 4; ++i) af[i] = *(const v8s*)&As[(wm * 64 + i * 16 + lr) * 32 + lk];
#pragma unroll
    for (int j = 0; j < 4; ++j) bf[j] = *(const v8s*)&Bs[(wn * 64 + j * 16 + lr) * 32 + lk];
#pragma unroll
    for (int i = 0; i < 4; ++i)
#pragma unroll
      for (int j = 0; j < 4; ++j)
        acc[i][j] = __builtin_amdgcn_mfma_f32_16x16x32_bf16(af[i], bf[j], acc[i][j], 0, 0, 0);
    __syncthreads();
  }
  const int lrow = (lane >> 4) * 4;
#pragma unroll
  for (int i = 0; i < 4; ++i) {
    const int rbase = r0 + wm * 64 + i * 16 + lrow;
    const int t = rbase >> 5, c0 = rbase & 31;
    const float w = wg[t];
#pragma unroll
    for (int j = 0; j < 4; ++j) {
      const int n = n0 + wn * 64 + j * 16 + lr;
      const int mI = n >> 1;
      float* dst = (n & 1) ? fwi : fwr;
      float4 v = {acc[i][j][0] * w, acc[i][j][1] * w, acc[i][j][2] * w, acc[i][j][3] * w};
      *(float4*)&dst[((size_t)mI * NT + t) * NC + c0] = v;
    }
  }
}

// ---------------------------------------------------------------- K2: flm (l >= m only), fp32
DEVFN void k2_flm(const float* __restrict__ leg, const float* __restrict__ fwr,
                  const float* __restrict__ fwi, float* __restrict__ flr,
                  float* __restrict__ fli) {
  const int m = blockIdx.x;
  const int l = m + blockIdx.y * 8 + (threadIdx.x >> 5);
  const int c = threadIdx.x & 31;
  if (l >= LL) return;
  const float* lg = leg + ((size_t)(l * MM2 + 127 + m)) * NT;
  const float* fr = fwr + (size_t)m * NT * NC + c;
  const float* fi = fwi + (size_t)m * NT * NC + c;
  float ar = 0.f, ai = 0.f;
  for (int t = 0; t < NT; t += 4) {
    const float4 b4 = *(const float4*)(lg + t);   // 16B-aligned (t % 4 == 0)
    ar = fmaf(b4.x, fr[(t + 0) * NC], ar);
    ai = fmaf(b4.x, fi[(t + 0) * NC], ai);
    ar = fmaf(b4.y, fr[(t + 1) * NC], ar);
    ai = fmaf(b4.y, fi[(t + 1) * NC], ai);
    ar = fmaf(b4.z, fr[(t + 2) * NC], ar);
    ai = fmaf(b4.z, fi[(t + 2) * NC], ai);
    ar = fmaf(b4.w, fr[(t + 3) * NC], ar);
    ai = fmaf(b4.w, fi[(t + 3) * NC], ai);
  }
  flr[(m * LL + l) * NC + c] = ar;
  fli[(m * LL + l) * NC + c] = ai;
}

// ---------------------------------------------------------------- K3: channel mix — wave-per-(m,l) stream
// One wave handles one (m,l). Lanes: oo = lane&31, c-half = lane>>5.
// Fully-unrolled 16 c-iters x 4 dword streams -> ~16KB in flight per wave;
// grid (128,32) -> thousands of resident waves: HBM-latency covered, BW-bound.
DEVFN void k3_y(const float* __restrict__ wr, const float* __restrict__ wi,
                const float* __restrict__ flr, const float* __restrict__ fli,
                float* __restrict__ ya, float* __restrict__ yb) {
  const int m = blockIdx.x;
  const int wid = threadIdx.x >> 6;
  const int lane = threadIdx.x & 63;
  const int l = m + blockIdx.y * 4 + wid;
  if (l >= LL) return;
  const int oo = lane & 31;
  const int half = lane >> 5;
  const float s0 = (m > 0) ? 1.0f : 0.0f;
  const size_t bp = ((size_t)(l * MM2 + 127 + m) * NC) * NO + oo;
  const size_t bn = ((size_t)(l * MM2 + 127 - m) * NC) * NO + oo;
  const float* fr = flr + (size_t)(m * LL + l) * NC + half * 16;
  const float* fi = fli + (size_t)(m * LL + l) * NC + half * 16;
  float accA = 0.f, accB = 0.f;
#pragma unroll
  for (int u = 0; u < 16; ++u) {
    const size_t co = (size_t)(half * 16 + u) * NO;
    const float wrp = wr[bp + co];
    const float wrn = wr[bn + co];
    const float wip = wi[bp + co];
    const float win = wi[bn + co];
    const float fa = fr[u];
    const float fb = fi[u];
    const float wa = fmaf(s0, wrn, wrp);          // Wr+ + s0*Wr-
    const float wb = fmaf(s0, win, -wip);         // s0*Wi- - Wi+
    accA = fmaf(fa, wa, fmaf(fb, wb, accA));
    accB = fmaf(fa, wb, fmaf(-fb, wa, accB));
  }
  accA += __shfl_down(accA, 32);
  accB += __shfl_down(accB, 32);
  if (lane < 32) {
    ya[(size_t)(m * LL + l) * NO + oo] = accA;
    yb[(size_t)(m * LL + l) * NO + oo] = accB;
  }
}

// ---------------------------------------------------------------- K4: inverse Legendre -> Ut bf16
// Ut[r=(t*32+o)][k] : k=2m -> cos coeff, k=2m+1 -> sin coeff
DEVFN void k4_G(const float* __restrict__ leg, const float* __restrict__ ya,
                const float* __restrict__ yb, unsigned short* __restrict__ ut) {
  const int m = blockIdx.x;
  const int o = threadIdx.x & 31;
  const int tq = threadIdx.x >> 5;
  const int t0 = blockIdx.y * 32 + tq * 4;
  float aa[4] = {}, bb[4] = {};
  for (int l = m; l < LL; ++l) {
    const float4 g = *(const float4*)(leg + ((size_t)(l * MM2 + 127 + m)) * NT + t0);
    const float yav = ya[(m * LL + l) * NO + o];
    const float ybv = yb[(m * LL + l) * NO + o];
    aa[0] = fmaf(g.x, yav, aa[0]);  bb[0] = fmaf(g.x, ybv, bb[0]);
    aa[1] = fmaf(g.y, yav, aa[1]);  bb[1] = fmaf(g.y, ybv, bb[1]);
    aa[2] = fmaf(g.z, yav, aa[2]);  bb[2] = fmaf(g.z, ybv, bb[2]);
    aa[3] = fmaf(g.w, yav, aa[3]);  bb[3] = fmaf(g.w, ybv, bb[3]);
  }
#pragma unroll
  for (int i = 0; i < 4; ++i) {
    const unsigned int pk = (unsigned int)f2bf(aa[i]) | ((unsigned int)f2bf(bb[i]) << 16);
    *(unsigned int*)&ut[((size_t)((t0 + i) * 32 + o)) * 256 + 2 * m] = pk;
  }
}

// ---------------------------------------------------------------- K5: inverse DFT via MFMA (A=vt)
// D[p][r] = sum_k vt[p][k] * ut[r][k];  out[o][t][p] = D,  r=t*32+o   (M=512,N=8192,K=256)
DEVFN void k5_mfma(const unsigned short* __restrict__ ut,
                   const unsigned short* __restrict__ vt,
                   float* __restrict__ out) {
  __shared__ unsigned short As[128 * 32];  // vt tile (p rows)
  __shared__ unsigned short Bs[128 * 32];  // ut tile (r rows)
  const int tid = threadIdx.x;
  const int p0 = blockIdx.x * 128;
  const int r0 = blockIdx.y * 128;
  const int wid = tid >> 6, lane = tid & 63;
  const int wm = wid & 1, wn = wid >> 1;
  v4f acc[4][4];
#pragma unroll
  for (int i = 0; i < 4; ++i)
#pragma unroll
    for (int j = 0; j < 4; ++j) {
      acc[i][j][0] = 0.f; acc[i][j][1] = 0.f; acc[i][j][2] = 0.f; acc[i][j][3] = 0.f;
    }
  const int lr = lane & 15, lk = (lane >> 4) * 8;
  for (int k0 = 0; k0 < 256; k0 += 32) {
#pragma unroll
    for (int s = 0; s < 2; ++s) {
      const int chunk = tid + s * 256;
      const int row = chunk >> 2, c16 = chunk & 3;
      *(uint4*)&As[row * 32 + c16 * 8] =
          *(const uint4*)&vt[(size_t)(p0 + row) * 256 + k0 + c16 * 8];
      *(uint4*)&Bs[row * 32 + c16 * 8] =
          *(const uint4*)&ut[(size_t)(r0 + row) * 256 + k0 + c16 * 8];
    }
    __syncthreads();
    v8s af[4], bf[4];
#pragma unroll
    for (int i = 0; i < 4; ++i) af[i] = *(const v8s*)&As[(wm * 64 + i * 16 + lr) * 32 + lk];
#pragma unroll
    for (int j = 0; j < 4; ++j) bf[j] = *(const v8s*)&Bs[(wn * 64 + j * 16 + lr) * 32 + lk];
#pragma unroll
    for (int i = 0; i < 4; ++i)
#pragma unroll
      for (int j = 0; j < 4; ++j)
        acc[i][j] = __builtin_amdgcn_mfma_f32_16x16x32_bf16(af[i], bf[j], acc[i][j], 0, 0, 0);
    __syncthreads();
  }
  const int lrow = (lane >> 4) * 4;
#pragma unroll
  for (int i = 0; i < 4; ++i) {
    const int pbase = p0 + wm * 64 + i * 16 + lrow;
#pragma unroll
    for (int j = 0; j < 4; ++j) {
      const int r = r0 + wn * 64 + j * 16 + lr;
      const int t = r >> 5, o = r & 31;
      float4 v = {acc[i][j][0], acc[i][j][1], acc[i][j][2], acc[i][j][3]};
      *(float4*)&out[((size_t)o * NT + t) * NP + pbase] = v;
    }
  }
}

// ---------------------------------------------------------------- launch
extern "C" void kernel_launch(void* const* d_in, const int* in_sizes, int n_in,
                              void* d_out, int out_size, void* d_ws, size_t ws_size,
                              hipStream_t stream) {
  const float* x   = (const float*)d_in[0];
  const float* wr  = (const float*)d_in[1];
  const float* wi  = (const float*)d_in[2];
  const float* leg = (const float*)d_in[3];
  const float* wg  = (const float*)d_in[4];
  float* out = (float*)d_out;

  unsigned short* tw1t = (unsigned short*)d_ws;     // 256*512   = 131072
  unsigned short* vt   = tw1t + 131072;             // 512*256   = 131072
  unsigned short* xb   = vt + 131072;               // 8192*512  = 4194304
  unsigned short* ut   = xb + 4194304;              // 8192*256  = 2097152
  float* fwr = (float*)(ut + 2097152);              // 128*256*32 = 1048576
  float* fwi = fwr + 1048576;
  float* flr = fwi + 1048576;                       // 128*128*32 = 524288
  float* fli = flr + 524288;
  float* ya  = fli + 524288;
  float* yb  = ya + 524288;                         // total ~29.9 MB

  hipLaunchKernelGGL(kp_prep, dim3(2560), dim3(256), 0, stream, x, tw1t, vt, xb);
  hipLaunchKernelGGL(k1_mfma, dim3(64, 2), dim3(256), 0, stream, xb, tw1t, wg, fwr, fwi);
  hipLaunchKernelGGL(k2_flm, dim3(128, 16), dim3(256), 0, stream, leg, fwr, fwi, flr, fli);
  hipLaunchKernelGGL(k3_y, dim3(128, 32), dim3(256), 0, stream, wr, wi, flr, fli, ya, yb);
  hipLaunchKernelGGL(k4_G, dim3(128, 8), dim3(256), 0, stream, leg, ya, yb, ut);
  hipLaunchKernelGGL(k5_mfma, dim3(4, 64), dim3(256), 0, stream, ut, vt, out);
}